// Round 2
// baseline (919.441 us; speedup 1.0000x reference)
//
#include <hip/hip_runtime.h>

// Problem constants (fixed by setup_inputs): B=64 samples, C=50 parts, N=65536 points.
#define BB 64
#define CC 50
#define NN 65536
#define TPB 256
#define PTS 16                    // points per thread (4x float4 per channel -> high MLP)
#define CHUNK (TPB * PTS)         // 4096 points per block
#define NCHUNK (NN / CHUNK)       // 16 chunks per sample

// ShapeNet class -> contiguous part-id range boundaries.
__constant__ int c_starts[17] = {0, 4, 6, 8, 12, 16, 19, 22, 24, 28, 30, 36, 38, 41, 44, 47, 50};

// Masked argmax over the class's valid part range + per-(b,part) histograms.
// pred_cnt and inter share one packed 32-bit LDS counter (cnt | inter<<16):
// per-block counts are <= 4096 so 16-bit fields cannot overflow.
__global__ __launch_bounds__(TPB) void miou_main(
    const float* __restrict__ logits,   // [B, C, N]
    const int*   __restrict__ targets,  // [B, N]
    const int*   __restrict__ cls,      // [B]
    float*       __restrict__ out,      // [1 + B*N]
    int*         __restrict__ cnt)      // [3][B][C]: inter, pred_cnt, gt_cnt
{
    __shared__ int s_pi[CC];   // pred_cnt | (inter << 16)
    __shared__ int s_gt[CC];

    const int b     = (int)blockIdx.x / NCHUNK;
    const int chunk = (int)blockIdx.x % NCHUNK;

    for (int i = threadIdx.x; i < CC; i += TPB) { s_pi[i] = 0; s_gt[i] = 0; }
    __syncthreads();

    const int cl = cls[b];
    const int s0 = c_starts[cl], s1 = c_starts[cl + 1];
    const int n0 = chunk * CHUNK + (int)threadIdx.x * PTS;

    const float* lg = logits + (size_t)b * CC * NN + n0;

    // argmax over c in [s0, s1): ascending c, strict '>' keeps FIRST max
    // (matches jnp.argmax tie-breaking).
    float4 best[4];
    int4   idx[4];
    {
        const float4* p = (const float4*)(lg + (size_t)s0 * NN);
        #pragma unroll
        for (int q = 0; q < 4; ++q) { best[q] = p[q]; idx[q] = make_int4(s0, s0, s0, s0); }
    }
    for (int c = s0 + 1; c < s1; ++c) {
        const float4* p = (const float4*)(lg + (size_t)c * NN);
        #pragma unroll
        for (int q = 0; q < 4; ++q) {
            float4 v = p[q];
            if (v.x > best[q].x) { best[q].x = v.x; idx[q].x = c; }
            if (v.y > best[q].y) { best[q].y = v.y; idx[q].y = c; }
            if (v.z > best[q].z) { best[q].z = v.z; idx[q].z = c; }
            if (v.w > best[q].w) { best[q].w = v.w; idx[q].w = c; }
        }
    }

    const int4* tg = (const int4*)(targets + (size_t)b * NN + n0);
    float*      po = out + 1 + (size_t)b * NN + n0;   // offset 1 breaks 16B align -> scalar stores

    #pragma unroll
    for (int q = 0; q < 4; ++q) {
        int4 t = tg[q];
        __builtin_nontemporal_store((float)idx[q].x, po + q * 4 + 0);
        __builtin_nontemporal_store((float)idx[q].y, po + q * 4 + 1);
        __builtin_nontemporal_store((float)idx[q].z, po + q * 4 + 2);
        __builtin_nontemporal_store((float)idx[q].w, po + q * 4 + 3);
        atomicAdd(&s_pi[idx[q].x], 1 + ((int)(idx[q].x == t.x) << 16));
        atomicAdd(&s_pi[idx[q].y], 1 + ((int)(idx[q].y == t.y) << 16));
        atomicAdd(&s_pi[idx[q].z], 1 + ((int)(idx[q].z == t.z) << 16));
        atomicAdd(&s_pi[idx[q].w], 1 + ((int)(idx[q].w == t.w) << 16));
        atomicAdd(&s_gt[t.x], 1);
        atomicAdd(&s_gt[t.y], 1);
        atomicAdd(&s_gt[t.z], 1);
        atomicAdd(&s_gt[t.w], 1);
    }

    __syncthreads();
    for (int i = threadIdx.x; i < CC; i += TPB) {
        int pi = s_pi[i], g = s_gt[i];
        if (pi) {
            atomicAdd(&cnt[b * CC + i],           pi >> 16);      // inter
            atomicAdd(&cnt[BB * CC + b * CC + i], pi & 0xffff);   // pred_cnt
        }
        if (g) atomicAdd(&cnt[2 * BB * CC + b * CC + i], g);
    }
}

// Finalize: one wave, lane b = sample b. IoU over valid parts, then wave
// shuffle-reduce to the scalar mean.
__global__ __launch_bounds__(64) void miou_final(
    const int* __restrict__ cls,
    const int* __restrict__ cnt,
    float*     __restrict__ out)
{
    const int b  = threadIdx.x;
    const int cl = cls[b];
    const int s0 = c_starts[cl], s1 = c_starts[cl + 1];
    float sum = 0.f;
    for (int c = s0; c < s1; ++c) {
        float inter = (float)cnt[b * CC + c];
        float pc    = (float)cnt[BB * CC + b * CC + c];
        float gc    = (float)cnt[2 * BB * CC + b * CC + c];
        float un    = pc + gc - inter;
        float iou   = (un == 0.f) ? 1.f : inter / fmaxf(un, 1.f);
        sum += iou;
    }
    float biou = sum / (float)(s1 - s0);
    for (int off = 32; off; off >>= 1) biou += __shfl_down(biou, off);
    if (b == 0) out[0] = biou / (float)BB;
}

extern "C" void kernel_launch(void* const* d_in, const int* in_sizes, int n_in,
                              void* d_out, int out_size, void* d_ws, size_t ws_size,
                              hipStream_t stream) {
    const float* logits  = (const float*)d_in[0];
    const int*   targets = (const int*)d_in[1];
    const int*   cls     = (const int*)d_in[2];
    float*       out     = (float*)d_out;
    int*         cnt     = (int*)d_ws;

    // counts workspace is re-poisoned to 0xAA before every launch — zero it.
    hipMemsetAsync(cnt, 0, 3 * BB * CC * sizeof(int), stream);

    miou_main<<<dim3(BB * NCHUNK), dim3(TPB), 0, stream>>>(logits, targets, cls, out, cnt);
    miou_final<<<1, 64, 0, stream>>>(cls, cnt, out);
}